// Round 11
// baseline (363.852 us; speedup 1.0000x reference)
//
#include <hip/hip_runtime.h>
#include <hip/hip_fp16.h>
#include <math.h>

#define B_   16
#define T_   256
#define V_   25
#define D_   128
#define H_   8
#define DH   16
#define BV_  (B_*V_)        // 400
#define MAXT 300
#define NREL (2*MAXT-1)     // 599
#define LOG2E 1.44269504088896f

typedef __attribute__((ext_vector_type(8))) short short8;
typedef __attribute__((ext_vector_type(4))) float f32x4;
typedef __attribute__((ext_vector_type(2))) __fp16 fp16x2;
typedef __attribute__((ext_vector_type(4))) _Float16 half4;
typedef __attribute__((ext_vector_type(8))) _Float16 half8;

__device__ inline short f2bf(float f) {
  union { float f; unsigned u; } a; a.f = f;
  unsigned r = (a.u + 0x7FFF + ((a.u >> 16) & 1)) >> 16;   // RNE
  return (short)r;
}

__device__ inline float fast_exp2(float x) {
#if __has_builtin(__builtin_amdgcn_exp2f)
  return __builtin_amdgcn_exp2f(x);     // v_exp_f32 (hardware op IS 2^x)
#else
  return exp2f(x);
#endif
}

// gelu(u) ~= u * sigmoid(1.595769*u*(1 + 0.044715*u^2)); |err| <= ~3e-4
__device__ inline float gelu_fast(float u) {
  float s = u * fmaf(0.0713548162726f, u*u, 1.5957691216057f);
  return u * __builtin_amdgcn_rcpf(1.0f + __expf(-s));
}

// ---------------- K0: weight prep (R4 layout) -------------------------------
// qkv_wt, pwt: bf16 [N][K]; w1t: f16 [N=512][K=128];
// w2t: f16 FRAG-LINEAR [ot(8)][hn(32)][lane(64)][r(4)]:
//   element = w2[k = hn*16 + (lane>>4)*4 + r][n = ot*16 + (lane&15)]
__global__ __launch_bounds__(256) void k0_prep(
    const float* __restrict__ qkv_w, const float* __restrict__ pw,
    const float* __restrict__ w1,    const float* __restrict__ w2,
    short* __restrict__ qkv_wt, short* __restrict__ pwt,
    _Float16* __restrict__ w1t, _Float16* __restrict__ w2t)
{
  int i = blockIdx.x*256 + threadIdx.x;
  if (i < 384*128) { int n = i >> 7, k = i & 127; qkv_wt[i] = f2bf(qkv_w[k*384 + n]); }
  if (i < 128*128) { int n = i >> 7, k = i & 127; pwt[i]    = f2bf(pw[k*128 + n]); }
  if (i < 512*128) { int n = i >> 7, k = i & 127; w1t[i]    = (_Float16)w1[k*512 + n]; }
  if (i < 128*512) {
    int r = i & 3, lane = (i >> 2) & 63, hn = (i >> 8) & 31, ot = i >> 13;
    int k = hn*16 + (lane >> 4)*4 + r;
    int n = ot*16 + (lane & 15);
    w2t[i] = (_Float16)w2[k*128 + n];
  }
}

// ---------------- K1: LN1 + QKV (MFMA, 64 tok/block) + q/k head-norm --------
// Tile remap it*4+wave: every wave gets 2q+2k+2v (4 norm tiles) instead of
// wave0 carrying 6 norm-heavy q tiles while wave3 (v only) idles.
__global__ __launch_bounds__(256) void k1_ln_qkv(
    const float* __restrict__ x, const float* __restrict__ g1, const float* __restrict__ b1,
    const short* __restrict__ qkv_wt, const float* __restrict__ qkv_b,
    const float* __restrict__ logit_scale,
    _Float16* __restrict__ qb, _Float16* __restrict__ kb, _Float16* __restrict__ vt)
{
  __shared__ short xn[64][136];
  const int tid = threadIdx.x;
  const int bv  = blockIdx.x / (T_/64);
  const int t0  = (blockIdx.x % (T_/64)) * 64;
  const int b   = bv / V_, v = bv % V_;

  { // LN: 16 threads/token, 4 reps of 16 tokens
    const int j = tid & 15;
    float4 gA = *(const float4*)(g1 + j*8), gB = *(const float4*)(g1 + j*8 + 4);
    float4 bA = *(const float4*)(b1 + j*8), bB = *(const float4*)(b1 + j*8 + 4);
    float gg[8] = {gA.x,gA.y,gA.z,gA.w,gB.x,gB.y,gB.z,gB.w};
    float bb[8] = {bA.x,bA.y,bA.z,bA.w,bB.x,bB.y,bB.z,bB.w};
    for (int rep = 0; rep < 4; ++rep) {
      const int tok = rep*16 + (tid >> 4);
      const float* xp = x + (((size_t)b*T_ + (t0+tok))*V_ + v)*D_ + j*8;
      float4 a0 = *(const float4*)xp;
      float4 a1 = *(const float4*)(xp+4);
      float e[8] = {a0.x,a0.y,a0.z,a0.w,a1.x,a1.y,a1.z,a1.w};
      float s = 0.f;
      #pragma unroll
      for (int q = 0; q < 8; ++q) s += e[q];
      #pragma unroll
      for (int m = 1; m < 16; m <<= 1) s += __shfl_xor(s, m, 16);
      float mean = s * (1.0f/128.0f);
      float s2 = 0.f;
      #pragma unroll
      for (int q = 0; q < 8; ++q) { float d = e[q]-mean; s2 += d*d; }
      #pragma unroll
      for (int m = 1; m < 16; m <<= 1) s2 += __shfl_xor(s2, m, 16);
      float rstd = rsqrtf(s2*(1.0f/128.0f) + 1e-5f);
      short8 o;
      #pragma unroll
      for (int q = 0; q < 8; ++q) o[q] = f2bf((e[q]-mean)*rstd*gg[q] + bb[q]);
      *(short8*)&xn[tok][j*8] = o;
    }
  }
  __syncthreads();

  const int wave = tid >> 6, lane = tid & 63;
  const int col = lane & 15, quad = lane >> 4;
  short8 af[4][4];
  #pragma unroll
  for (int tt = 0; tt < 4; ++tt)
    #pragma unroll
    for (int kk = 0; kk < 4; ++kk)
      af[tt][kk] = *(const short8*)&xn[tt*16+col][kk*32 + quad*8];

  for (int it = 0; it < 6; ++it) {
    const int tile = it*4 + wave;           // balanced: each wave 2q+2k+2v
    const int n0 = tile*16;
    short8 bf[4];
    #pragma unroll
    for (int kk = 0; kk < 4; ++kk)
      bf[kk] = *(const short8*)(qkv_wt + (size_t)(n0+col)*128 + kk*32 + quad*8);
    f32x4 acc[4] = {{0.f,0.f,0.f,0.f},{0.f,0.f,0.f,0.f},{0.f,0.f,0.f,0.f},{0.f,0.f,0.f,0.f}};
    #pragma unroll
    for (int kk = 0; kk < 4; ++kk)
      #pragma unroll
      for (int tt = 0; tt < 4; ++tt)
        acc[tt] = __builtin_amdgcn_mfma_f32_16x16x32_bf16(af[tt][kk], bf[kk], acc[tt], 0, 0, 0);
    const float bias = qkv_b[n0+col];
    const int h = tile & 7;
    const size_t bh = (size_t)bv*H_ + h;
    if (tile < 16) {
      const float scale = (tile < 8)
        ? __expf(fminf(logit_scale[h], 4.605170185988091f)) * 0.25f * LOG2E : 1.0f;
      #pragma unroll
      for (int tt = 0; tt < 4; ++tt) {
        float val[4], inv[4];
        #pragma unroll
        for (int r = 0; r < 4; ++r) {
          val[r] = acc[tt][r] + bias;
          float s = val[r]*val[r];
          #pragma unroll
          for (int m = 1; m < 16; m <<= 1) s += __shfl_xor(s, m, 16);
          inv[r] = 1.0f / fmaxf(sqrtf(s), 1e-12f);
        }
        const size_t obase = (bh*T_ + (t0 + tt*16 + quad*4))*DH + col;
        if (tile < 8) {
          #pragma unroll
          for (int r = 0; r < 4; ++r) qb[obase + (size_t)r*DH] = (_Float16)(val[r]*inv[r]*scale);
        } else {
          #pragma unroll
          for (int r = 0; r < 4; ++r) kb[obase + (size_t)r*DH] = (_Float16)(val[r]*inv[r]);
        }
      }
    } else {
      #pragma unroll
      for (int tt = 0; tt < 4; ++tt) {
        half4 vh;
        #pragma unroll
        for (int r = 0; r < 4; ++r) vh[r] = (_Float16)(acc[tt][r] + bias);
        *(half4*)(vt + bh*4096 + (size_t)(t0/16 + tt)*256 + col*16 + quad*4) = vh;
      }
    }
  }
}

// ---------------- K2: attention via MFMA (S^T trick); bf16 output -----------
__global__ __launch_bounds__(256) void k2_attn(
    const float* __restrict__ rel_pos_bias,
    const _Float16* __restrict__ qb, const _Float16* __restrict__ kb,
    const _Float16* __restrict__ vt, short* __restrict__ xattn)
{
  __shared__ float bias_s[NREL + 1];
  const int tid = threadIdx.x;
  const int bh  = blockIdx.x;          // bv*H + h
  const int h   = bh & (H_-1);
  const int bv  = bh >> 3;
  for (int j = tid; j < NREL; j += 256) bias_s[j] = rel_pos_bias[h*NREL + j] * LOG2E;
  __syncthreads();

  const int wave = tid >> 6, lane = tid & 63;
  const int nn = lane & 15, quad = lane >> 4;
  const size_t qkbase = (size_t)bh * (T_*DH);
  const size_t vbase  = (size_t)bh * 4096;

  half4 qf[4];
  #pragma unroll
  for (int tt = 0; tt < 4; ++tt)
    qf[tt] = *(const half4*)(qb + qkbase + (size_t)(wave*64 + tt*16 + nn)*DH + quad*4);

  f32x4 o[4];
  #pragma unroll
  for (int tt = 0; tt < 4; ++tt) o[tt] = (f32x4){0.f,0.f,0.f,0.f};
  float lsum[4] = {0.f,0.f,0.f,0.f};

  half4 kf = *(const half4*)(kb + qkbase + (size_t)nn*DH + quad*4);
  half4 vf = *(const half4*)(vt + vbase + (size_t)nn*16 + quad*4);

  for (int s16 = 0; s16 < 16; ++s16) {
    half4 kf_n, vf_n;
    if (s16 < 15) {
      kf_n = *(const half4*)(kb + qkbase + (size_t)((s16+1)*16 + nn)*DH + quad*4);
      vf_n = *(const half4*)(vt + vbase + (size_t)(s16+1)*256 + nn*16 + quad*4);
    }
    #pragma unroll
    for (int tt = 0; tt < 4; ++tt) {
      f32x4 c = {0.f,0.f,0.f,0.f};
      c = __builtin_amdgcn_mfma_f32_16x16x16f16(kf, qf[tt], c, 0, 0, 0);
      const int ib = (wave*64 + tt*16 + nn) - (s16*16 + quad*4) + (MAXT-1);
      float p0 = fast_exp2(c[0] + bias_s[ib]);
      float p1 = fast_exp2(c[1] + bias_s[ib - 1]);
      float p2 = fast_exp2(c[2] + bias_s[ib - 2]);
      float p3 = fast_exp2(c[3] + bias_s[ib - 3]);
      lsum[tt] += (p0 + p1) + (p2 + p3);
      fp16x2 lo = __builtin_amdgcn_cvt_pkrtz(p0, p1);
      fp16x2 hi = __builtin_amdgcn_cvt_pkrtz(p2, p3);
      union { struct { fp16x2 a, b; } p; half4 h; } cv;
      cv.p.a = lo; cv.p.b = hi;
      o[tt] = __builtin_amdgcn_mfma_f32_16x16x16f16(cv.h, vf, o[tt], 0, 0, 0);
    }
    kf = kf_n; vf = vf_n;
  }

  #pragma unroll
  for (int tt = 0; tt < 4; ++tt) {
    float l = lsum[tt];
    l += __shfl_xor(l, 16);
    l += __shfl_xor(l, 32);
    float rinv = 1.0f / l;
    #pragma unroll
    for (int r = 0; r < 4; ++r) {
      float inv = __shfl(rinv, quad*4 + r, 16);
      const int t = wave*64 + tt*16 + quad*4 + r;
      xattn[((size_t)bv*T_ + t)*D_ + h*DH + nn] = f2bf(o[tt][r] * inv);
    }
  }
}

// ---------------- K3: attn @ proj_w + proj_b + residual (64 tok/block) ------
__global__ __launch_bounds__(256) void k3_proj(
    const float* __restrict__ x, const short* __restrict__ xattn,
    const short* __restrict__ pwt, const float* __restrict__ proj_b,
    float* __restrict__ xf2)
{
  const int tid = threadIdx.x;
  const int bv  = blockIdx.x / (T_/64);
  const int t0  = (blockIdx.x % (T_/64)) * 64;
  const int b   = bv / V_, v = bv % V_;
  const int wave = tid >> 6, lane = tid & 63;
  const int col = lane & 15, quad = lane >> 4;

  short8 af[4][4];
  #pragma unroll
  for (int tt = 0; tt < 4; ++tt)
    #pragma unroll
    for (int kk = 0; kk < 4; ++kk)
      af[tt][kk] = *(const short8*)(xattn
                    + ((size_t)bv*T_ + t0 + tt*16 + col)*D_ + kk*32 + quad*8);

  for (int it = 0; it < 2; ++it) {
    const int n0 = (wave*2 + it)*16;
    short8 bf[4];
    #pragma unroll
    for (int kk = 0; kk < 4; ++kk)
      bf[kk] = *(const short8*)(pwt + (size_t)(n0+col)*128 + kk*32 + quad*8);
    f32x4 acc[4] = {{0.f,0.f,0.f,0.f},{0.f,0.f,0.f,0.f},{0.f,0.f,0.f,0.f},{0.f,0.f,0.f,0.f}};
    #pragma unroll
    for (int kk = 0; kk < 4; ++kk)
      #pragma unroll
      for (int tt = 0; tt < 4; ++tt)
        acc[tt] = __builtin_amdgcn_mfma_f32_16x16x32_bf16(af[tt][kk], bf[kk], acc[tt], 0, 0, 0);
    const float pbv = proj_b[n0+col];
    #pragma unroll
    for (int tt = 0; tt < 4; ++tt)
      #pragma unroll
      for (int r = 0; r < 4; ++r) {
        const int t = t0 + tt*16 + quad*4 + r;
        float res = x[(((size_t)b*T_ + t)*V_ + v)*D_ + n0 + col];
        xf2[((size_t)bv*T_ + t)*D_ + n0 + col] = acc[tt][r] + pbv + res;
      }
  }
}

// ---------------- K4: LN2 + FFN, BARRIER-FREE direct-global weights ---------
// R1's direct-load structure, minus R1's fatal flag: plain __launch_bounds__
// (the (256,4) variant snapped hipcc to a 64-VGPR tier -> no load pipelining,
// 116 us). Double-buffered register prefetch (w1a/w2a <-> w1b/w2b): hn+1's 12
// weight loads issue before hn's ~270-cycle MFMA+gelu body -> L2 latency
// (weights = 262 KB L2-resident set) hides under compute. Zero in-loop
// barriers, zero weight LDS, zero bank conflicts; waves fully independent
// after the LN2 prologue. LDS = y_s only (34.8 KB).
__global__ __launch_bounds__(256) void k4_ffn(
    const float* __restrict__ xf2, const float* __restrict__ g2, const float* __restrict__ b2,
    const _Float16* __restrict__ w1t, const float* __restrict__ fb1,
    const _Float16* __restrict__ w2t, const float* __restrict__ fb2,
    float* __restrict__ out)
{
  __shared__ _Float16 y_s[128][136];
  const int tid = threadIdx.x;
  const int bv  = blockIdx.x / (T_/128);
  const int t0  = (blockIdx.x % (T_/128)) * 128;
  const int b   = bv / V_, v = bv % V_;

  { // LN2 for 128 tokens -> y_s (f16)
    const int j = tid & 15;
    float4 gA = *(const float4*)(g2 + j*8), gB = *(const float4*)(g2 + j*8 + 4);
    float4 bA = *(const float4*)(b2 + j*8), bB = *(const float4*)(b2 + j*8 + 4);
    float gg[8] = {gA.x,gA.y,gA.z,gA.w,gB.x,gB.y,gB.z,gB.w};
    float bb[8] = {bA.x,bA.y,bA.z,bA.w,bB.x,bB.y,bB.z,bB.w};
    for (int rep = 0; rep < 8; ++rep) {
      const int tok = rep*16 + (tid >> 4);
      const float* xp = xf2 + ((size_t)bv*T_ + t0+tok)*D_ + j*8;
      float4 a0 = *(const float4*)xp;
      float4 a1 = *(const float4*)(xp+4);
      float e[8] = {a0.x,a0.y,a0.z,a0.w,a1.x,a1.y,a1.z,a1.w};
      float s = 0.f;
      #pragma unroll
      for (int q = 0; q < 8; ++q) s += e[q];
      #pragma unroll
      for (int m = 1; m < 16; m <<= 1) s += __shfl_xor(s, m, 16);
      float mean = s * (1.0f/128.0f);
      float s2 = 0.f;
      #pragma unroll
      for (int q = 0; q < 8; ++q) { float d = e[q]-mean; s2 += d*d; }
      #pragma unroll
      for (int m = 1; m < 16; m <<= 1) s2 += __shfl_xor(s2, m, 16);
      float rstd = rsqrtf(s2*(1.0f/128.0f) + 1e-5f);
      half8 o;
      #pragma unroll
      for (int q = 0; q < 8; ++q) o[q] = (_Float16)((e[q]-mean)*rstd*gg[q] + bb[q]);
      *(half8*)&y_s[tok][j*8] = o;
    }
  }
  __syncthreads();

  const int wave = tid >> 6, lane = tid & 63;
  const int col = lane & 15, quad = lane >> 4;

  // Y B-frags hoisted for the whole hidden loop
  half8 yf[2][4];
  #pragma unroll
  for (int tt = 0; tt < 2; ++tt)
    #pragma unroll
    for (int kk = 0; kk < 4; ++kk)
      yf[tt][kk] = *(const half8*)&y_s[wave*32 + tt*16 + col][kk*32 + quad*8];

  f32x4 acc2[2][8];
  #pragma unroll
  for (int tt = 0; tt < 2; ++tt)
    #pragma unroll
    for (int ot = 0; ot < 8; ++ot) acc2[tt][ot] = (f32x4){0.f,0.f,0.f,0.f};

  half8 w1a[4], w1b[4];
  half4 w2a[8], w2b[8];

  auto LOADW = [&](int hn, half8 (&w1d)[4], half4 (&w2d)[8]) {
    #pragma unroll
    for (int kk = 0; kk < 4; ++kk)
      w1d[kk] = *(const half8*)(w1t + (size_t)(hn*16+col)*128 + kk*32 + quad*8);
    #pragma unroll
    for (int ot = 0; ot < 8; ++ot)
      w2d[ot] = *(const half4*)(w2t + ((size_t)(ot*32 + hn)*64 + lane)*4);
  };
  auto BODY = [&](int hn, half8 (&w1f)[4], half4 (&w2f)[8],
                  half8 (&w1n)[4], half4 (&w2n)[8]) {
    if (hn + 1 < 32) LOADW(hn + 1, w1n, w2n);      // prefetch before compute
    f32x4 c0 = {0.f,0.f,0.f,0.f}, c1 = {0.f,0.f,0.f,0.f};
    #pragma unroll
    for (int kk = 0; kk < 4; ++kk) {
      c0 = __builtin_amdgcn_mfma_f32_16x16x32_f16(w1f[kk], yf[0][kk], c0, 0, 0, 0);
      c1 = __builtin_amdgcn_mfma_f32_16x16x32_f16(w1f[kk], yf[1][kk], c1, 0, 0, 0);
    }
    const f32x4 b1v = *(const f32x4*)(fb1 + hn*16 + quad*4);
    half4 pa0, pa1;
    #pragma unroll
    for (int r = 0; r < 4; ++r) {
      pa0[r] = (_Float16)gelu_fast(c0[r] + b1v[r]);
      pa1[r] = (_Float16)gelu_fast(c1[r] + b1v[r]);
    }
    #pragma unroll
    for (int ot = 0; ot < 8; ++ot) {
      acc2[0][ot] = __builtin_amdgcn_mfma_f32_16x16x16f16(pa0, w2f[ot], acc2[0][ot], 0, 0, 0);
      acc2[1][ot] = __builtin_amdgcn_mfma_f32_16x16x16f16(pa1, w2f[ot], acc2[1][ot], 0, 0, 0);
    }
  };

  LOADW(0, w1a, w2a);
  for (int hn = 0; hn < 32; hn += 2) {
    BODY(hn,     w1a, w2a, w1b, w2b);
    BODY(hn + 1, w1b, w2b, w1a, w2a);
  }

  // epilogue: + fb2 + residual (re-read xf2), store to permuted out
  const int tw = t0 + wave*32;
  #pragma unroll
  for (int tt = 0; tt < 2; ++tt)
    #pragma unroll
    for (int ot = 0; ot < 8; ++ot) {
      const float bo = fb2[ot*16 + col];
      #pragma unroll
      for (int r = 0; r < 4; ++r) {
        const int t = tw + tt*16 + quad*4 + r;
        float val = acc2[tt][ot][r] + bo + xf2[((size_t)bv*T_ + t)*D_ + ot*16 + col];
        out[(((size_t)b*T_ + t)*V_ + v)*D_ + ot*16 + col] = val;
      }
    }
}

extern "C" void kernel_launch(void* const* d_in, const int* in_sizes, int n_in,
                              void* d_out, int out_size, void* d_ws, size_t ws_size,
                              hipStream_t stream)
{
  (void)in_sizes; (void)n_in; (void)out_size; (void)ws_size;
  const float* x     = (const float*)d_in[0];
  const float* g1    = (const float*)d_in[1];
  const float* b1    = (const float*)d_in[2];
  const float* qkv_w = (const float*)d_in[3];
  const float* qkv_b = (const float*)d_in[4];
  const float* pw    = (const float*)d_in[5];
  const float* pb    = (const float*)d_in[6];
  const float* ls    = (const float*)d_in[7];
  const float* rpb   = (const float*)d_in[8];
  const float* g2    = (const float*)d_in[9];
  const float* b2    = (const float*)d_in[10];
  const float* w1    = (const float*)d_in[11];
  const float* fb1   = (const float*)d_in[12];
  const float* w2    = (const float*)d_in[13];
  const float* fb2   = (const float*)d_in[14];
  float* out = (float*)d_out;

  const size_t n = (size_t)BV_*T_*D_;          // 13,107,200
  char* ws = (char*)d_ws;
  _Float16* qb  = (_Float16*)ws;               // n fp16
  _Float16* kb  = (_Float16*)(ws + n*2);       // n fp16
  float*    xf2 = (float*)(ws + n*4);          // n fp32 (proj+residual out)
  _Float16* vt  = (_Float16*)(ws + n*8);       // n fp16, PV-B-frag layout
  short*    xab = (short*)(ws + n*10);         // n bf16 (attn out)
  short*    qkv_wt = (short*)(ws + n*12);      // 384*128 bf16
  short*    pwt    = qkv_wt + 384*128;         // 128*128 bf16
  _Float16* w1t    = (_Float16*)(pwt + 128*128);   // 512*128 f16
  _Float16* w2t    = w1t + 512*128;                // 128*512 f16 frag-linear

  k0_prep  <<<256,          dim3(256), 0, stream>>>(qkv_w, pw, w1, w2, qkv_wt, pwt, w1t, w2t);
  k1_ln_qkv<<<BV_*(T_/64),  dim3(256), 0, stream>>>(x, g1, b1, qkv_wt, qkv_b, ls, qb, kb, vt);
  k2_attn  <<<BV_*H_,       dim3(256), 0, stream>>>(rpb, qb, kb, vt, xab);
  k3_proj  <<<BV_*(T_/64),  dim3(256), 0, stream>>>(x, xab, pwt, pb, xf2);
  k4_ffn   <<<BV_*(T_/128), dim3(256), 0, stream>>>(xf2, g2, b2, w1t, fb1, w2t, fb2, out);
}

// Round 12
// 313.069 us; speedup vs baseline: 1.1622x; 1.1622x over previous
//
#include <hip/hip_runtime.h>
#include <hip/hip_fp16.h>
#include <math.h>

#define B_   16
#define T_   256
#define V_   25
#define D_   128
#define H_   8
#define DH   16
#define BV_  (B_*V_)        // 400
#define MAXT 300
#define NREL (2*MAXT-1)     // 599
#define LOG2E 1.44269504088896f

typedef __attribute__((ext_vector_type(8))) short short8;
typedef __attribute__((ext_vector_type(4))) float f32x4;
typedef __attribute__((ext_vector_type(2))) __fp16 fp16x2;
typedef __attribute__((ext_vector_type(4))) _Float16 half4;
typedef __attribute__((ext_vector_type(8))) _Float16 half8;

__device__ inline short f2bf(float f) {
  union { float f; unsigned u; } a; a.f = f;
  unsigned r = (a.u + 0x7FFF + ((a.u >> 16) & 1)) >> 16;   // RNE
  return (short)r;
}

__device__ inline float fast_exp2(float x) {
#if __has_builtin(__builtin_amdgcn_exp2f)
  return __builtin_amdgcn_exp2f(x);     // v_exp_f32 (hardware op IS 2^x)
#else
  return exp2f(x);
#endif
}

// gelu(u) ~= u * sigmoid(1.595769*u*(1 + 0.044715*u^2)); |err| <= ~3e-4
__device__ inline float gelu_fast(float u) {
  float s = u * fmaf(0.0713548162726f, u*u, 1.5957691216057f);
  return u * __builtin_amdgcn_rcpf(1.0f + __expf(-s));
}

// ---------------- K0: weight prep (R4 layout) -------------------------------
// qkv_wt, pwt: bf16 [N][K]; w1t: f16 [N=512][K=128];
// w2t: f16 FRAG-LINEAR [ot(8)][hn(32)][lane(64)][r(4)]:
//   element = w2[k = hn*16 + (lane>>4)*4 + r][n = ot*16 + (lane&15)]
__global__ __launch_bounds__(256) void k0_prep(
    const float* __restrict__ qkv_w, const float* __restrict__ pw,
    const float* __restrict__ w1,    const float* __restrict__ w2,
    short* __restrict__ qkv_wt, short* __restrict__ pwt,
    _Float16* __restrict__ w1t, _Float16* __restrict__ w2t)
{
  int i = blockIdx.x*256 + threadIdx.x;
  if (i < 384*128) { int n = i >> 7, k = i & 127; qkv_wt[i] = f2bf(qkv_w[k*384 + n]); }
  if (i < 128*128) { int n = i >> 7, k = i & 127; pwt[i]    = f2bf(pw[k*128 + n]); }
  if (i < 512*128) { int n = i >> 7, k = i & 127; w1t[i]    = (_Float16)w1[k*512 + n]; }
  if (i < 128*512) {
    int r = i & 3, lane = (i >> 2) & 63, hn = (i >> 8) & 31, ot = i >> 13;
    int k = hn*16 + (lane >> 4)*4 + r;
    int n = ot*16 + (lane & 15);
    w2t[i] = (_Float16)w2[k*128 + n];
  }
}

// ---------------- K1: LN1 + QKV (MFMA, 64 tok/block) + q/k head-norm --------
// Tile remap it*4+wave: every wave gets 2q+2k+2v (4 norm tiles) instead of
// wave0 carrying 6 norm-heavy q tiles while wave3 (v only) idles.
__global__ __launch_bounds__(256) void k1_ln_qkv(
    const float* __restrict__ x, const float* __restrict__ g1, const float* __restrict__ b1,
    const short* __restrict__ qkv_wt, const float* __restrict__ qkv_b,
    const float* __restrict__ logit_scale,
    _Float16* __restrict__ qb, _Float16* __restrict__ kb, _Float16* __restrict__ vt)
{
  __shared__ short xn[64][136];
  const int tid = threadIdx.x;
  const int bv  = blockIdx.x / (T_/64);
  const int t0  = (blockIdx.x % (T_/64)) * 64;
  const int b   = bv / V_, v = bv % V_;

  { // LN: 16 threads/token, 4 reps of 16 tokens
    const int j = tid & 15;
    float4 gA = *(const float4*)(g1 + j*8), gB = *(const float4*)(g1 + j*8 + 4);
    float4 bA = *(const float4*)(b1 + j*8), bB = *(const float4*)(b1 + j*8 + 4);
    float gg[8] = {gA.x,gA.y,gA.z,gA.w,gB.x,gB.y,gB.z,gB.w};
    float bb[8] = {bA.x,bA.y,bA.z,bA.w,bB.x,bB.y,bB.z,bB.w};
    for (int rep = 0; rep < 4; ++rep) {
      const int tok = rep*16 + (tid >> 4);
      const float* xp = x + (((size_t)b*T_ + (t0+tok))*V_ + v)*D_ + j*8;
      float4 a0 = *(const float4*)xp;
      float4 a1 = *(const float4*)(xp+4);
      float e[8] = {a0.x,a0.y,a0.z,a0.w,a1.x,a1.y,a1.z,a1.w};
      float s = 0.f;
      #pragma unroll
      for (int q = 0; q < 8; ++q) s += e[q];
      #pragma unroll
      for (int m = 1; m < 16; m <<= 1) s += __shfl_xor(s, m, 16);
      float mean = s * (1.0f/128.0f);
      float s2 = 0.f;
      #pragma unroll
      for (int q = 0; q < 8; ++q) { float d = e[q]-mean; s2 += d*d; }
      #pragma unroll
      for (int m = 1; m < 16; m <<= 1) s2 += __shfl_xor(s2, m, 16);
      float rstd = rsqrtf(s2*(1.0f/128.0f) + 1e-5f);
      short8 o;
      #pragma unroll
      for (int q = 0; q < 8; ++q) o[q] = f2bf((e[q]-mean)*rstd*gg[q] + bb[q]);
      *(short8*)&xn[tok][j*8] = o;
    }
  }
  __syncthreads();

  const int wave = tid >> 6, lane = tid & 63;
  const int col = lane & 15, quad = lane >> 4;
  short8 af[4][4];
  #pragma unroll
  for (int tt = 0; tt < 4; ++tt)
    #pragma unroll
    for (int kk = 0; kk < 4; ++kk)
      af[tt][kk] = *(const short8*)&xn[tt*16+col][kk*32 + quad*8];

  for (int it = 0; it < 6; ++it) {
    const int tile = it*4 + wave;           // balanced: each wave 2q+2k+2v
    const int n0 = tile*16;
    short8 bf[4];
    #pragma unroll
    for (int kk = 0; kk < 4; ++kk)
      bf[kk] = *(const short8*)(qkv_wt + (size_t)(n0+col)*128 + kk*32 + quad*8);
    f32x4 acc[4] = {{0.f,0.f,0.f,0.f},{0.f,0.f,0.f,0.f},{0.f,0.f,0.f,0.f},{0.f,0.f,0.f,0.f}};
    #pragma unroll
    for (int kk = 0; kk < 4; ++kk)
      #pragma unroll
      for (int tt = 0; tt < 4; ++tt)
        acc[tt] = __builtin_amdgcn_mfma_f32_16x16x32_bf16(af[tt][kk], bf[kk], acc[tt], 0, 0, 0);
    const float bias = qkv_b[n0+col];
    const int h = tile & 7;
    const size_t bh = (size_t)bv*H_ + h;
    if (tile < 16) {
      const float scale = (tile < 8)
        ? __expf(fminf(logit_scale[h], 4.605170185988091f)) * 0.25f * LOG2E : 1.0f;
      #pragma unroll
      for (int tt = 0; tt < 4; ++tt) {
        float val[4], inv[4];
        #pragma unroll
        for (int r = 0; r < 4; ++r) {
          val[r] = acc[tt][r] + bias;
          float s = val[r]*val[r];
          #pragma unroll
          for (int m = 1; m < 16; m <<= 1) s += __shfl_xor(s, m, 16);
          inv[r] = 1.0f / fmaxf(sqrtf(s), 1e-12f);
        }
        const size_t obase = (bh*T_ + (t0 + tt*16 + quad*4))*DH + col;
        if (tile < 8) {
          #pragma unroll
          for (int r = 0; r < 4; ++r) qb[obase + (size_t)r*DH] = (_Float16)(val[r]*inv[r]*scale);
        } else {
          #pragma unroll
          for (int r = 0; r < 4; ++r) kb[obase + (size_t)r*DH] = (_Float16)(val[r]*inv[r]);
        }
      }
    } else {
      #pragma unroll
      for (int tt = 0; tt < 4; ++tt) {
        half4 vh;
        #pragma unroll
        for (int r = 0; r < 4; ++r) vh[r] = (_Float16)(acc[tt][r] + bias);
        *(half4*)(vt + bh*4096 + (size_t)(t0/16 + tt)*256 + col*16 + quad*4) = vh;
      }
    }
  }
}

// ---------------- K2: attention via MFMA (S^T trick); bf16 output -----------
__global__ __launch_bounds__(256) void k2_attn(
    const float* __restrict__ rel_pos_bias,
    const _Float16* __restrict__ qb, const _Float16* __restrict__ kb,
    const _Float16* __restrict__ vt, short* __restrict__ xattn)
{
  __shared__ float bias_s[NREL + 1];
  const int tid = threadIdx.x;
  const int bh  = blockIdx.x;          // bv*H + h
  const int h   = bh & (H_-1);
  const int bv  = bh >> 3;
  for (int j = tid; j < NREL; j += 256) bias_s[j] = rel_pos_bias[h*NREL + j] * LOG2E;
  __syncthreads();

  const int wave = tid >> 6, lane = tid & 63;
  const int nn = lane & 15, quad = lane >> 4;
  const size_t qkbase = (size_t)bh * (T_*DH);
  const size_t vbase  = (size_t)bh * 4096;

  half4 qf[4];
  #pragma unroll
  for (int tt = 0; tt < 4; ++tt)
    qf[tt] = *(const half4*)(qb + qkbase + (size_t)(wave*64 + tt*16 + nn)*DH + quad*4);

  f32x4 o[4];
  #pragma unroll
  for (int tt = 0; tt < 4; ++tt) o[tt] = (f32x4){0.f,0.f,0.f,0.f};
  float lsum[4] = {0.f,0.f,0.f,0.f};

  half4 kf = *(const half4*)(kb + qkbase + (size_t)nn*DH + quad*4);
  half4 vf = *(const half4*)(vt + vbase + (size_t)nn*16 + quad*4);

  for (int s16 = 0; s16 < 16; ++s16) {
    half4 kf_n, vf_n;
    if (s16 < 15) {
      kf_n = *(const half4*)(kb + qkbase + (size_t)((s16+1)*16 + nn)*DH + quad*4);
      vf_n = *(const half4*)(vt + vbase + (size_t)(s16+1)*256 + nn*16 + quad*4);
    }
    #pragma unroll
    for (int tt = 0; tt < 4; ++tt) {
      f32x4 c = {0.f,0.f,0.f,0.f};
      c = __builtin_amdgcn_mfma_f32_16x16x16f16(kf, qf[tt], c, 0, 0, 0);
      const int ib = (wave*64 + tt*16 + nn) - (s16*16 + quad*4) + (MAXT-1);
      float p0 = fast_exp2(c[0] + bias_s[ib]);
      float p1 = fast_exp2(c[1] + bias_s[ib - 1]);
      float p2 = fast_exp2(c[2] + bias_s[ib - 2]);
      float p3 = fast_exp2(c[3] + bias_s[ib - 3]);
      lsum[tt] += (p0 + p1) + (p2 + p3);
      fp16x2 lo = __builtin_amdgcn_cvt_pkrtz(p0, p1);
      fp16x2 hi = __builtin_amdgcn_cvt_pkrtz(p2, p3);
      union { struct { fp16x2 a, b; } p; half4 h; } cv;
      cv.p.a = lo; cv.p.b = hi;
      o[tt] = __builtin_amdgcn_mfma_f32_16x16x16f16(cv.h, vf, o[tt], 0, 0, 0);
    }
    kf = kf_n; vf = vf_n;
  }

  #pragma unroll
  for (int tt = 0; tt < 4; ++tt) {
    float l = lsum[tt];
    l += __shfl_xor(l, 16);
    l += __shfl_xor(l, 32);
    float rinv = 1.0f / l;
    #pragma unroll
    for (int r = 0; r < 4; ++r) {
      float inv = __shfl(rinv, quad*4 + r, 16);
      const int t = wave*64 + tt*16 + quad*4 + r;
      xattn[((size_t)bv*T_ + t)*D_ + h*DH + nn] = f2bf(o[tt][r] * inv);
    }
  }
}

// ---------------- K3: attn @ proj_w + proj_b + residual (64 tok/block) ------
__global__ __launch_bounds__(256) void k3_proj(
    const float* __restrict__ x, const short* __restrict__ xattn,
    const short* __restrict__ pwt, const float* __restrict__ proj_b,
    float* __restrict__ xf2)
{
  const int tid = threadIdx.x;
  const int bv  = blockIdx.x / (T_/64);
  const int t0  = (blockIdx.x % (T_/64)) * 64;
  const int b   = bv / V_, v = bv % V_;
  const int wave = tid >> 6, lane = tid & 63;
  const int col = lane & 15, quad = lane >> 4;

  short8 af[4][4];
  #pragma unroll
  for (int tt = 0; tt < 4; ++tt)
    #pragma unroll
    for (int kk = 0; kk < 4; ++kk)
      af[tt][kk] = *(const short8*)(xattn
                    + ((size_t)bv*T_ + t0 + tt*16 + col)*D_ + kk*32 + quad*8);

  for (int it = 0; it < 2; ++it) {
    const int n0 = (wave*2 + it)*16;
    short8 bf[4];
    #pragma unroll
    for (int kk = 0; kk < 4; ++kk)
      bf[kk] = *(const short8*)(pwt + (size_t)(n0+col)*128 + kk*32 + quad*8);
    f32x4 acc[4] = {{0.f,0.f,0.f,0.f},{0.f,0.f,0.f,0.f},{0.f,0.f,0.f,0.f},{0.f,0.f,0.f,0.f}};
    #pragma unroll
    for (int kk = 0; kk < 4; ++kk)
      #pragma unroll
      for (int tt = 0; tt < 4; ++tt)
        acc[tt] = __builtin_amdgcn_mfma_f32_16x16x32_bf16(af[tt][kk], bf[kk], acc[tt], 0, 0, 0);
    const float pbv = proj_b[n0+col];
    #pragma unroll
    for (int tt = 0; tt < 4; ++tt)
      #pragma unroll
      for (int r = 0; r < 4; ++r) {
        const int t = t0 + tt*16 + quad*4 + r;
        float res = x[(((size_t)b*T_ + t)*V_ + v)*D_ + n0 + col];
        xf2[((size_t)bv*T_ + t)*D_ + n0 + col] = acc[tt][r] + pbv + res;
      }
  }
}

// ---------------- K4: LN2 + FFN, aliased LDS + async reg-prefetch (FROZEN) --
// R7/R10 form: 128 tok/block, LDS-staged weights w/ async reg-prefetch,
// weight buffers alias dead y_s (34.8 KB). This is the measured local
// optimum: direct-global variants (R1: 116us, R11: 132us — 4x per-wave load
// traffic, no LDS sharing), capacity/grid/barrier variants (R2/R5/R8) all
// equal-or-worse than this structure's ~82 us.
__global__ __launch_bounds__(256) void k4_ffn(
    const float* __restrict__ xf2, const float* __restrict__ g2, const float* __restrict__ b2,
    const _Float16* __restrict__ w1t, const float* __restrict__ fb1,
    const _Float16* __restrict__ w2t, const float* __restrict__ fb2,
    float* __restrict__ out)
{
  __shared__ __align__(16) char smem[34816];
  _Float16 (*y_s)[136] = (_Float16 (*)[136])smem;      // prologue only
  _Float16 (*w1c)[136] = (_Float16 (*)[136])smem;      // aliases y_s after yf read
  _Float16 *w2c = (_Float16*)(smem + 64*136*2);        // 17408 B offset, 16 KB

  const int tid = threadIdx.x;
  const int bv  = blockIdx.x / (T_/128);
  const int t0  = (blockIdx.x % (T_/128)) * 128;
  const int b   = bv / V_, v = bv % V_;

  // ---- issue chunk-0 weight loads immediately (overlap with LN2) ----
  half8 p_w1[4], p_w2[4];
  #pragma unroll
  for (int j = 0; j < 4; ++j) {
    const int u = j*256 + tid;
    p_w1[j] = *(const half8*)(w1t + (size_t)(u >> 4)*128 + (u & 15)*8);
    p_w2[j] = *(const half8*)(w2t + (size_t)((u >> 7)*32 + ((u >> 5) & 3))*256 + (u & 31)*8);
  }

  { // LN2 for 128 tokens -> y_s (f16)
    const int j = tid & 15;
    float4 gA = *(const float4*)(g2 + j*8), gB = *(const float4*)(g2 + j*8 + 4);
    float4 bA = *(const float4*)(b2 + j*8), bB = *(const float4*)(b2 + j*8 + 4);
    float gg[8] = {gA.x,gA.y,gA.z,gA.w,gB.x,gB.y,gB.z,gB.w};
    float bb[8] = {bA.x,bA.y,bA.z,bA.w,bB.x,bB.y,bB.z,bB.w};
    for (int rep = 0; rep < 8; ++rep) {
      const int tok = rep*16 + (tid >> 4);
      const float* xp = xf2 + ((size_t)bv*T_ + t0+tok)*D_ + j*8;
      float4 a0 = *(const float4*)xp;
      float4 a1 = *(const float4*)(xp+4);
      float e[8] = {a0.x,a0.y,a0.z,a0.w,a1.x,a1.y,a1.z,a1.w};
      float s = 0.f;
      #pragma unroll
      for (int q = 0; q < 8; ++q) s += e[q];
      #pragma unroll
      for (int m = 1; m < 16; m <<= 1) s += __shfl_xor(s, m, 16);
      float mean = s * (1.0f/128.0f);
      float s2 = 0.f;
      #pragma unroll
      for (int q = 0; q < 8; ++q) { float d = e[q]-mean; s2 += d*d; }
      #pragma unroll
      for (int m = 1; m < 16; m <<= 1) s2 += __shfl_xor(s2, m, 16);
      float rstd = rsqrtf(s2*(1.0f/128.0f) + 1e-5f);
      half8 o;
      #pragma unroll
      for (int q = 0; q < 8; ++q) o[q] = (_Float16)((e[q]-mean)*rstd*gg[q] + bb[q]);
      *(half8*)&y_s[tok][j*8] = o;
    }
  }
  __syncthreads();

  const int wave = tid >> 6, lane = tid & 63;
  const int col = lane & 15, quad = lane >> 4;

  // Y B-frags hoisted for the whole hidden loop; y_s dead afterwards
  half8 yf[2][4];
  #pragma unroll
  for (int tt = 0; tt < 2; ++tt)
    #pragma unroll
    for (int kk = 0; kk < 4; ++kk)
      yf[tt][kk] = *(const half8*)&y_s[wave*32 + tt*16 + col][kk*32 + quad*8];
  __syncthreads();   // all yf reads done before w1c/w2c overwrite y_s

  f32x4 acc2[2][8];
  #pragma unroll
  for (int tt = 0; tt < 2; ++tt)
    #pragma unroll
    for (int ot = 0; ot < 8; ++ot) acc2[tt][ot] = (f32x4){0.f,0.f,0.f,0.f};

  for (int c = 0; c < 8; ++c) {
    // commit staged chunk c to LDS
    #pragma unroll
    for (int j = 0; j < 4; ++j) {
      const int u = j*256 + tid;
      *(half8*)&w1c[u >> 4][(u & 15)*8] = p_w1[j];
      *(half8*)&w2c[(size_t)u*8]        = p_w2[j];
    }
    __syncthreads();

    // issue chunk c+1 loads (no use until next iteration's commit)
    if (c < 7) {
      #pragma unroll
      for (int j = 0; j < 4; ++j) {
        const int u = j*256 + tid;
        p_w1[j] = *(const half8*)(w1t + (size_t)((c+1)*64 + (u >> 4))*128 + (u & 15)*8);
        p_w2[j] = *(const half8*)(w2t + (size_t)((u >> 7)*32 + (c+1)*4 + ((u >> 5) & 3))*256 + (u & 31)*8);
      }
    }

    #pragma unroll
    for (int ht = 0; ht < 4; ++ht) {
      half8 w1f[4];
      #pragma unroll
      for (int kk = 0; kk < 4; ++kk)
        w1f[kk] = *(const half8*)&w1c[ht*16+col][kk*32 + quad*8];
      f32x4 c0 = {0.f,0.f,0.f,0.f}, c1 = {0.f,0.f,0.f,0.f};
      #pragma unroll
      for (int kk = 0; kk < 4; ++kk) {
        c0 = __builtin_amdgcn_mfma_f32_16x16x32_f16(w1f[kk], yf[0][kk], c0, 0, 0, 0);
        c1 = __builtin_amdgcn_mfma_f32_16x16x32_f16(w1f[kk], yf[1][kk], c1, 0, 0, 0);
      }
      const int hn = c*4 + ht;
      const f32x4 b1v = *(const f32x4*)(fb1 + hn*16 + quad*4);
      half4 pa0, pa1;
      #pragma unroll
      for (int r = 0; r < 4; ++r) {
        pa0[r] = (_Float16)gelu_fast(c0[r] + b1v[r]);
        pa1[r] = (_Float16)gelu_fast(c1[r] + b1v[r]);
      }
      #pragma unroll
      for (int ot = 0; ot < 8; ++ot) {
        half4 w2f = *(const half4*)&w2c[((ot*4 + ht)*64 + lane)*4];
        acc2[0][ot] = __builtin_amdgcn_mfma_f32_16x16x16f16(pa0, w2f, acc2[0][ot], 0, 0, 0);
        acc2[1][ot] = __builtin_amdgcn_mfma_f32_16x16x16f16(pa1, w2f, acc2[1][ot], 0, 0, 0);
      }
    }
    __syncthreads();   // chunk's LDS reads complete before next commit
  }

  // epilogue: + fb2 + residual (re-read xf2), store to permuted out
  const int tw = t0 + wave*32;
  #pragma unroll
  for (int tt = 0; tt < 2; ++tt)
    #pragma unroll
    for (int ot = 0; ot < 8; ++ot) {
      const float bo = fb2[ot*16 + col];
      #pragma unroll
      for (int r = 0; r < 4; ++r) {
        const int t = tw + tt*16 + quad*4 + r;
        float val = acc2[tt][ot][r] + bo + xf2[((size_t)bv*T_ + t)*D_ + ot*16 + col];
        out[(((size_t)b*T_ + t)*V_ + v)*D_ + ot*16 + col] = val;
      }
    }
}

extern "C" void kernel_launch(void* const* d_in, const int* in_sizes, int n_in,
                              void* d_out, int out_size, void* d_ws, size_t ws_size,
                              hipStream_t stream)
{
  (void)in_sizes; (void)n_in; (void)out_size; (void)ws_size;
  const float* x     = (const float*)d_in[0];
  const float* g1    = (const float*)d_in[1];
  const float* b1    = (const float*)d_in[2];
  const float* qkv_w = (const float*)d_in[3];
  const float* qkv_b = (const float*)d_in[4];
  const float* pw    = (const float*)d_in[5];
  const float* pb    = (const float*)d_in[6];
  const float* ls    = (const float*)d_in[7];
  const float* rpb   = (const float*)d_in[8];
  const float* g2    = (const float*)d_in[9];
  const float* b2    = (const float*)d_in[10];
  const float* w1    = (const float*)d_in[11];
  const float* fb1   = (const float*)d_in[12];
  const float* w2    = (const float*)d_in[13];
  const float* fb2   = (const float*)d_in[14];
  float* out = (float*)d_out;

  const size_t n = (size_t)BV_*T_*D_;          // 13,107,200
  char* ws = (char*)d_ws;
  _Float16* qb  = (_Float16*)ws;               // n fp16
  _Float16* kb  = (_Float16*)(ws + n*2);       // n fp16
  float*    xf2 = (float*)(ws + n*4);          // n fp32 (proj+residual out)
  _Float16* vt  = (_Float16*)(ws + n*8);       // n fp16, PV-B-frag layout
  short*    xab = (short*)(ws + n*10);         // n bf16 (attn out)
  short*    qkv_wt = (short*)(ws + n*12);      // 384*128 bf16
  short*    pwt    = qkv_wt + 384*128;         // 128*128 bf16
  _Float16* w1t    = (_Float16*)(pwt + 128*128);   // 512*128 f16
  _Float16* w2t    = w1t + 512*128;                // 128*512 f16 frag-linear

  k0_prep  <<<256,          dim3(256), 0, stream>>>(qkv_w, pw, w1, w2, qkv_wt, pwt, w1t, w2t);
  k1_ln_qkv<<<BV_*(T_/64),  dim3(256), 0, stream>>>(x, g1, b1, qkv_wt, qkv_b, ls, qb, kb, vt);
  k2_attn  <<<BV_*H_,       dim3(256), 0, stream>>>(rpb, qb, kb, vt, xab);
  k3_proj  <<<BV_*(T_/64),  dim3(256), 0, stream>>>(x, xab, pwt, pb, xf2);
  k4_ffn   <<<BV_*(T_/128), dim3(256), 0, stream>>>(xf2, g2, b2, w1t, fb1, w2t, fb2, out);
}

// Round 13
// 310.889 us; speedup vs baseline: 1.1704x; 1.0070x over previous
//
#include <hip/hip_runtime.h>
#include <hip/hip_fp16.h>
#include <math.h>

#define B_   16
#define T_   256
#define V_   25
#define D_   128
#define H_   8
#define DH   16
#define BV_  (B_*V_)        // 400
#define MAXT 300
#define NREL (2*MAXT-1)     // 599
#define LOG2E 1.44269504088896f

typedef __attribute__((ext_vector_type(8))) short short8;
typedef __attribute__((ext_vector_type(4))) float f32x4;
typedef __attribute__((ext_vector_type(2))) __fp16 fp16x2;
typedef __attribute__((ext_vector_type(4))) _Float16 half4;
typedef __attribute__((ext_vector_type(8))) _Float16 half8;

__device__ inline short f2bf(float f) {
  union { float f; unsigned u; } a; a.f = f;
  unsigned r = (a.u + 0x7FFF + ((a.u >> 16) & 1)) >> 16;   // RNE
  return (short)r;
}

__device__ inline float fast_exp2(float x) {
#if __has_builtin(__builtin_amdgcn_exp2f)
  return __builtin_amdgcn_exp2f(x);     // v_exp_f32 (hardware op IS 2^x)
#else
  return exp2f(x);
#endif
}

// gelu(u) ~= u * sigmoid(1.595769*u*(1 + 0.044715*u^2)); |err| <= ~3e-4
__device__ inline float gelu_fast(float u) {
  float s = u * fmaf(0.0713548162726f, u*u, 1.5957691216057f);
  return u * __builtin_amdgcn_rcpf(1.0f + __expf(-s));
}

// ---------------- K0: weight prep (R4 layout) -------------------------------
// qkv_wt, pwt: bf16 [N][K]; w1t: f16 [N=512][K=128];
// w2t: f16 FRAG-LINEAR [ot(8)][hn(32)][lane(64)][r(4)]:
//   element = w2[k = hn*16 + (lane>>4)*4 + r][n = ot*16 + (lane&15)]
__global__ __launch_bounds__(256) void k0_prep(
    const float* __restrict__ qkv_w, const float* __restrict__ pw,
    const float* __restrict__ w1,    const float* __restrict__ w2,
    short* __restrict__ qkv_wt, short* __restrict__ pwt,
    _Float16* __restrict__ w1t, _Float16* __restrict__ w2t)
{
  int i = blockIdx.x*256 + threadIdx.x;
  if (i < 384*128) { int n = i >> 7, k = i & 127; qkv_wt[i] = f2bf(qkv_w[k*384 + n]); }
  if (i < 128*128) { int n = i >> 7, k = i & 127; pwt[i]    = f2bf(pw[k*128 + n]); }
  if (i < 512*128) { int n = i >> 7, k = i & 127; w1t[i]    = (_Float16)w1[k*512 + n]; }
  if (i < 128*512) {
    int r = i & 3, lane = (i >> 2) & 63, hn = (i >> 8) & 31, ot = i >> 13;
    int k = hn*16 + (lane >> 4)*4 + r;
    int n = ot*16 + (lane & 15);
    w2t[i] = (_Float16)w2[k*128 + n];
  }
}

// ---------------- K1: LN1 + QKV (MFMA, 64 tok/block) + q/k head-norm --------
// Tile remap it*4+wave: every wave gets 2q+2k+2v (4 norm tiles) instead of
// wave0 carrying 6 norm-heavy q tiles while wave3 (v only) idles.
__global__ __launch_bounds__(256) void k1_ln_qkv(
    const float* __restrict__ x, const float* __restrict__ g1, const float* __restrict__ b1,
    const short* __restrict__ qkv_wt, const float* __restrict__ qkv_b,
    const float* __restrict__ logit_scale,
    _Float16* __restrict__ qb, _Float16* __restrict__ kb, _Float16* __restrict__ vt)
{
  __shared__ short xn[64][136];
  const int tid = threadIdx.x;
  const int bv  = blockIdx.x / (T_/64);
  const int t0  = (blockIdx.x % (T_/64)) * 64;
  const int b   = bv / V_, v = bv % V_;

  { // LN: 16 threads/token, 4 reps of 16 tokens
    const int j = tid & 15;
    float4 gA = *(const float4*)(g1 + j*8), gB = *(const float4*)(g1 + j*8 + 4);
    float4 bA = *(const float4*)(b1 + j*8), bB = *(const float4*)(b1 + j*8 + 4);
    float gg[8] = {gA.x,gA.y,gA.z,gA.w,gB.x,gB.y,gB.z,gB.w};
    float bb[8] = {bA.x,bA.y,bA.z,bA.w,bB.x,bB.y,bB.z,bB.w};
    for (int rep = 0; rep < 4; ++rep) {
      const int tok = rep*16 + (tid >> 4);
      const float* xp = x + (((size_t)b*T_ + (t0+tok))*V_ + v)*D_ + j*8;
      float4 a0 = *(const float4*)xp;
      float4 a1 = *(const float4*)(xp+4);
      float e[8] = {a0.x,a0.y,a0.z,a0.w,a1.x,a1.y,a1.z,a1.w};
      float s = 0.f;
      #pragma unroll
      for (int q = 0; q < 8; ++q) s += e[q];
      #pragma unroll
      for (int m = 1; m < 16; m <<= 1) s += __shfl_xor(s, m, 16);
      float mean = s * (1.0f/128.0f);
      float s2 = 0.f;
      #pragma unroll
      for (int q = 0; q < 8; ++q) { float d = e[q]-mean; s2 += d*d; }
      #pragma unroll
      for (int m = 1; m < 16; m <<= 1) s2 += __shfl_xor(s2, m, 16);
      float rstd = rsqrtf(s2*(1.0f/128.0f) + 1e-5f);
      short8 o;
      #pragma unroll
      for (int q = 0; q < 8; ++q) o[q] = f2bf((e[q]-mean)*rstd*gg[q] + bb[q]);
      *(short8*)&xn[tok][j*8] = o;
    }
  }
  __syncthreads();

  const int wave = tid >> 6, lane = tid & 63;
  const int col = lane & 15, quad = lane >> 4;
  short8 af[4][4];
  #pragma unroll
  for (int tt = 0; tt < 4; ++tt)
    #pragma unroll
    for (int kk = 0; kk < 4; ++kk)
      af[tt][kk] = *(const short8*)&xn[tt*16+col][kk*32 + quad*8];

  for (int it = 0; it < 6; ++it) {
    const int tile = it*4 + wave;           // balanced: each wave 2q+2k+2v
    const int n0 = tile*16;
    short8 bf[4];
    #pragma unroll
    for (int kk = 0; kk < 4; ++kk)
      bf[kk] = *(const short8*)(qkv_wt + (size_t)(n0+col)*128 + kk*32 + quad*8);
    f32x4 acc[4] = {{0.f,0.f,0.f,0.f},{0.f,0.f,0.f,0.f},{0.f,0.f,0.f,0.f},{0.f,0.f,0.f,0.f}};
    #pragma unroll
    for (int kk = 0; kk < 4; ++kk)
      #pragma unroll
      for (int tt = 0; tt < 4; ++tt)
        acc[tt] = __builtin_amdgcn_mfma_f32_16x16x32_bf16(af[tt][kk], bf[kk], acc[tt], 0, 0, 0);
    const float bias = qkv_b[n0+col];
    const int h = tile & 7;
    const size_t bh = (size_t)bv*H_ + h;
    if (tile < 16) {
      const float scale = (tile < 8)
        ? __expf(fminf(logit_scale[h], 4.605170185988091f)) * 0.25f * LOG2E : 1.0f;
      #pragma unroll
      for (int tt = 0; tt < 4; ++tt) {
        float val[4], inv[4];
        #pragma unroll
        for (int r = 0; r < 4; ++r) {
          val[r] = acc[tt][r] + bias;
          float s = val[r]*val[r];
          #pragma unroll
          for (int m = 1; m < 16; m <<= 1) s += __shfl_xor(s, m, 16);
          inv[r] = 1.0f / fmaxf(sqrtf(s), 1e-12f);
        }
        const size_t obase = (bh*T_ + (t0 + tt*16 + quad*4))*DH + col;
        if (tile < 8) {
          #pragma unroll
          for (int r = 0; r < 4; ++r) qb[obase + (size_t)r*DH] = (_Float16)(val[r]*inv[r]*scale);
        } else {
          #pragma unroll
          for (int r = 0; r < 4; ++r) kb[obase + (size_t)r*DH] = (_Float16)(val[r]*inv[r]);
        }
      }
    } else {
      #pragma unroll
      for (int tt = 0; tt < 4; ++tt) {
        half4 vh;
        #pragma unroll
        for (int r = 0; r < 4; ++r) vh[r] = (_Float16)(acc[tt][r] + bias);
        *(half4*)(vt + bh*4096 + (size_t)(t0/16 + tt)*256 + col*16 + quad*4) = vh;
      }
    }
  }
}

// ---------------- K2: attention via MFMA (S^T trick); bf16 output -----------
// bias4_s[j] = {b[j],b[j-1],b[j-2],b[j-3]}*log2e (float4): the inner loop's
// 4 divergent ds_read_b32 (256 LDS instrs/wave ~ 1500cy, > MFMA issue) become
// ONE aligned ds_read_b128 (64 instrs/wave). Values bit-identical.
__global__ __launch_bounds__(256) void k2_attn(
    const float* __restrict__ rel_pos_bias,
    const _Float16* __restrict__ qb, const _Float16* __restrict__ kb,
    const _Float16* __restrict__ vt, short* __restrict__ xattn)
{
  __shared__ f32x4 bias4_s[NREL + 1];
  const int tid = threadIdx.x;
  const int bh  = blockIdx.x;          // bv*H + h
  const int h   = bh & (H_-1);
  const int bv  = bh >> 3;
  for (int j = tid; j < NREL; j += 256) {
    const float* rb = rel_pos_bias + h*NREL;
    f32x4 q;
    q[0] = rb[j] * LOG2E;
    q[1] = (j >= 1) ? rb[j-1] * LOG2E : 0.f;
    q[2] = (j >= 2) ? rb[j-2] * LOG2E : 0.f;
    q[3] = (j >= 3) ? rb[j-3] * LOG2E : 0.f;
    bias4_s[j] = q;
  }
  __syncthreads();

  const int wave = tid >> 6, lane = tid & 63;
  const int nn = lane & 15, quad = lane >> 4;
  const size_t qkbase = (size_t)bh * (T_*DH);
  const size_t vbase  = (size_t)bh * 4096;

  half4 qf[4];
  #pragma unroll
  for (int tt = 0; tt < 4; ++tt)
    qf[tt] = *(const half4*)(qb + qkbase + (size_t)(wave*64 + tt*16 + nn)*DH + quad*4);

  f32x4 o[4];
  #pragma unroll
  for (int tt = 0; tt < 4; ++tt) o[tt] = (f32x4){0.f,0.f,0.f,0.f};
  float lsum[4] = {0.f,0.f,0.f,0.f};

  half4 kf = *(const half4*)(kb + qkbase + (size_t)nn*DH + quad*4);
  half4 vf = *(const half4*)(vt + vbase + (size_t)nn*16 + quad*4);

  for (int s16 = 0; s16 < 16; ++s16) {
    half4 kf_n, vf_n;
    if (s16 < 15) {
      kf_n = *(const half4*)(kb + qkbase + (size_t)((s16+1)*16 + nn)*DH + quad*4);
      vf_n = *(const half4*)(vt + vbase + (size_t)(s16+1)*256 + nn*16 + quad*4);
    }
    #pragma unroll
    for (int tt = 0; tt < 4; ++tt) {
      f32x4 c = {0.f,0.f,0.f,0.f};
      c = __builtin_amdgcn_mfma_f32_16x16x16f16(kf, qf[tt], c, 0, 0, 0);
      const int ib = (wave*64 + tt*16 + nn) - (s16*16 + quad*4) + (MAXT-1);
      const f32x4 bb = bias4_s[ib];
      float p0 = fast_exp2(c[0] + bb[0]);
      float p1 = fast_exp2(c[1] + bb[1]);
      float p2 = fast_exp2(c[2] + bb[2]);
      float p3 = fast_exp2(c[3] + bb[3]);
      lsum[tt] += (p0 + p1) + (p2 + p3);
      fp16x2 lo = __builtin_amdgcn_cvt_pkrtz(p0, p1);
      fp16x2 hi = __builtin_amdgcn_cvt_pkrtz(p2, p3);
      union { struct { fp16x2 a, b; } p; half4 h; } cv;
      cv.p.a = lo; cv.p.b = hi;
      o[tt] = __builtin_amdgcn_mfma_f32_16x16x16f16(cv.h, vf, o[tt], 0, 0, 0);
    }
    kf = kf_n; vf = vf_n;
  }

  #pragma unroll
  for (int tt = 0; tt < 4; ++tt) {
    float l = lsum[tt];
    l += __shfl_xor(l, 16);
    l += __shfl_xor(l, 32);
    float rinv = 1.0f / l;
    #pragma unroll
    for (int r = 0; r < 4; ++r) {
      float inv = __shfl(rinv, quad*4 + r, 16);
      const int t = wave*64 + tt*16 + quad*4 + r;
      xattn[((size_t)bv*T_ + t)*D_ + h*DH + nn] = f2bf(o[tt][r] * inv);
    }
  }
}

// ---------------- K3: attn @ proj_w + proj_b + residual (64 tok/block) ------
__global__ __launch_bounds__(256) void k3_proj(
    const float* __restrict__ x, const short* __restrict__ xattn,
    const short* __restrict__ pwt, const float* __restrict__ proj_b,
    float* __restrict__ xf2)
{
  const int tid = threadIdx.x;
  const int bv  = blockIdx.x / (T_/64);
  const int t0  = (blockIdx.x % (T_/64)) * 64;
  const int b   = bv / V_, v = bv % V_;
  const int wave = tid >> 6, lane = tid & 63;
  const int col = lane & 15, quad = lane >> 4;

  short8 af[4][4];
  #pragma unroll
  for (int tt = 0; tt < 4; ++tt)
    #pragma unroll
    for (int kk = 0; kk < 4; ++kk)
      af[tt][kk] = *(const short8*)(xattn
                    + ((size_t)bv*T_ + t0 + tt*16 + col)*D_ + kk*32 + quad*8);

  for (int it = 0; it < 2; ++it) {
    const int n0 = (wave*2 + it)*16;
    short8 bf[4];
    #pragma unroll
    for (int kk = 0; kk < 4; ++kk)
      bf[kk] = *(const short8*)(pwt + (size_t)(n0+col)*128 + kk*32 + quad*8);
    f32x4 acc[4] = {{0.f,0.f,0.f,0.f},{0.f,0.f,0.f,0.f},{0.f,0.f,0.f,0.f},{0.f,0.f,0.f,0.f}};
    #pragma unroll
    for (int kk = 0; kk < 4; ++kk)
      #pragma unroll
      for (int tt = 0; tt < 4; ++tt)
        acc[tt] = __builtin_amdgcn_mfma_f32_16x16x32_bf16(af[tt][kk], bf[kk], acc[tt], 0, 0, 0);
    const float pbv = proj_b[n0+col];
    #pragma unroll
    for (int tt = 0; tt < 4; ++tt)
      #pragma unroll
      for (int r = 0; r < 4; ++r) {
        const int t = t0 + tt*16 + quad*4 + r;
        float res = x[(((size_t)b*T_ + t)*V_ + v)*D_ + n0 + col];
        xf2[((size_t)bv*T_ + t)*D_ + n0 + col] = acc[tt][r] + pbv + res;
      }
  }
}

// ---------------- K4: LN2 + FFN, aliased LDS + async reg-prefetch (FROZEN) --
// R7/R10 form: 128 tok/block, LDS-staged weights w/ async reg-prefetch,
// weight buffers alias dead y_s (34.8 KB). This is the measured local
// optimum: direct-global variants (R1: 116us, R11: 132us — 4x per-wave load
// traffic, no LDS sharing), capacity/grid/barrier variants (R2/R5/R8) all
// equal-or-worse than this structure's ~82 us.
__global__ __launch_bounds__(256) void k4_ffn(
    const float* __restrict__ xf2, const float* __restrict__ g2, const float* __restrict__ b2,
    const _Float16* __restrict__ w1t, const float* __restrict__ fb1,
    const _Float16* __restrict__ w2t, const float* __restrict__ fb2,
    float* __restrict__ out)
{
  __shared__ __align__(16) char smem[34816];
  _Float16 (*y_s)[136] = (_Float16 (*)[136])smem;      // prologue only
  _Float16 (*w1c)[136] = (_Float16 (*)[136])smem;      // aliases y_s after yf read
  _Float16 *w2c = (_Float16*)(smem + 64*136*2);        // 17408 B offset, 16 KB

  const int tid = threadIdx.x;
  const int bv  = blockIdx.x / (T_/128);
  const int t0  = (blockIdx.x % (T_/128)) * 128;
  const int b   = bv / V_, v = bv % V_;

  // ---- issue chunk-0 weight loads immediately (overlap with LN2) ----
  half8 p_w1[4], p_w2[4];
  #pragma unroll
  for (int j = 0; j < 4; ++j) {
    const int u = j*256 + tid;
    p_w1[j] = *(const half8*)(w1t + (size_t)(u >> 4)*128 + (u & 15)*8);
    p_w2[j] = *(const half8*)(w2t + (size_t)((u >> 7)*32 + ((u >> 5) & 3))*256 + (u & 31)*8);
  }

  { // LN2 for 128 tokens -> y_s (f16)
    const int j = tid & 15;
    float4 gA = *(const float4*)(g2 + j*8), gB = *(const float4*)(g2 + j*8 + 4);
    float4 bA = *(const float4*)(b2 + j*8), bB = *(const float4*)(b2 + j*8 + 4);
    float gg[8] = {gA.x,gA.y,gA.z,gA.w,gB.x,gB.y,gB.z,gB.w};
    float bb[8] = {bA.x,bA.y,bA.z,bA.w,bB.x,bB.y,bB.z,bB.w};
    for (int rep = 0; rep < 8; ++rep) {
      const int tok = rep*16 + (tid >> 4);
      const float* xp = xf2 + ((size_t)bv*T_ + t0+tok)*D_ + j*8;
      float4 a0 = *(const float4*)xp;
      float4 a1 = *(const float4*)(xp+4);
      float e[8] = {a0.x,a0.y,a0.z,a0.w,a1.x,a1.y,a1.z,a1.w};
      float s = 0.f;
      #pragma unroll
      for (int q = 0; q < 8; ++q) s += e[q];
      #pragma unroll
      for (int m = 1; m < 16; m <<= 1) s += __shfl_xor(s, m, 16);
      float mean = s * (1.0f/128.0f);
      float s2 = 0.f;
      #pragma unroll
      for (int q = 0; q < 8; ++q) { float d = e[q]-mean; s2 += d*d; }
      #pragma unroll
      for (int m = 1; m < 16; m <<= 1) s2 += __shfl_xor(s2, m, 16);
      float rstd = rsqrtf(s2*(1.0f/128.0f) + 1e-5f);
      half8 o;
      #pragma unroll
      for (int q = 0; q < 8; ++q) o[q] = (_Float16)((e[q]-mean)*rstd*gg[q] + bb[q]);
      *(half8*)&y_s[tok][j*8] = o;
    }
  }
  __syncthreads();

  const int wave = tid >> 6, lane = tid & 63;
  const int col = lane & 15, quad = lane >> 4;

  // Y B-frags hoisted for the whole hidden loop; y_s dead afterwards
  half8 yf[2][4];
  #pragma unroll
  for (int tt = 0; tt < 2; ++tt)
    #pragma unroll
    for (int kk = 0; kk < 4; ++kk)
      yf[tt][kk] = *(const half8*)&y_s[wave*32 + tt*16 + col][kk*32 + quad*8];
  __syncthreads();   // all yf reads done before w1c/w2c overwrite y_s

  f32x4 acc2[2][8];
  #pragma unroll
  for (int tt = 0; tt < 2; ++tt)
    #pragma unroll
    for (int ot = 0; ot < 8; ++ot) acc2[tt][ot] = (f32x4){0.f,0.f,0.f,0.f};

  for (int c = 0; c < 8; ++c) {
    // commit staged chunk c to LDS
    #pragma unroll
    for (int j = 0; j < 4; ++j) {
      const int u = j*256 + tid;
      *(half8*)&w1c[u >> 4][(u & 15)*8] = p_w1[j];
      *(half8*)&w2c[(size_t)u*8]        = p_w2[j];
    }
    __syncthreads();

    // issue chunk c+1 loads (no use until next iteration's commit)
    if (c < 7) {
      #pragma unroll
      for (int j = 0; j < 4; ++j) {
        const int u = j*256 + tid;
        p_w1[j] = *(const half8*)(w1t + (size_t)((c+1)*64 + (u >> 4))*128 + (u & 15)*8);
        p_w2[j] = *(const half8*)(w2t + (size_t)((u >> 7)*32 + (c+1)*4 + ((u >> 5) & 3))*256 + (u & 31)*8);
      }
    }

    #pragma unroll
    for (int ht = 0; ht < 4; ++ht) {
      half8 w1f[4];
      #pragma unroll
      for (int kk = 0; kk < 4; ++kk)
        w1f[kk] = *(const half8*)&w1c[ht*16+col][kk*32 + quad*8];
      f32x4 c0 = {0.f,0.f,0.f,0.f}, c1 = {0.f,0.f,0.f,0.f};
      #pragma unroll
      for (int kk = 0; kk < 4; ++kk) {
        c0 = __builtin_amdgcn_mfma_f32_16x16x32_f16(w1f[kk], yf[0][kk], c0, 0, 0, 0);
        c1 = __builtin_amdgcn_mfma_f32_16x16x32_f16(w1f[kk], yf[1][kk], c1, 0, 0, 0);
      }
      const int hn = c*4 + ht;
      const f32x4 b1v = *(const f32x4*)(fb1 + hn*16 + quad*4);
      half4 pa0, pa1;
      #pragma unroll
      for (int r = 0; r < 4; ++r) {
        pa0[r] = (_Float16)gelu_fast(c0[r] + b1v[r]);
        pa1[r] = (_Float16)gelu_fast(c1[r] + b1v[r]);
      }
      #pragma unroll
      for (int ot = 0; ot < 8; ++ot) {
        half4 w2f = *(const half4*)&w2c[((ot*4 + ht)*64 + lane)*4];
        acc2[0][ot] = __builtin_amdgcn_mfma_f32_16x16x16f16(pa0, w2f, acc2[0][ot], 0, 0, 0);
        acc2[1][ot] = __builtin_amdgcn_mfma_f32_16x16x16f16(pa1, w2f, acc2[1][ot], 0, 0, 0);
      }
    }
    __syncthreads();   // chunk's LDS reads complete before next commit
  }

  // epilogue: + fb2 + residual (re-read xf2), store to permuted out
  const int tw = t0 + wave*32;
  #pragma unroll
  for (int tt = 0; tt < 2; ++tt)
    #pragma unroll
    for (int ot = 0; ot < 8; ++ot) {
      const float bo = fb2[ot*16 + col];
      #pragma unroll
      for (int r = 0; r < 4; ++r) {
        const int t = tw + tt*16 + quad*4 + r;
        float val = acc2[tt][ot][r] + bo + xf2[((size_t)bv*T_ + t)*D_ + ot*16 + col];
        out[(((size_t)b*T_ + t)*V_ + v)*D_ + ot*16 + col] = val;
      }
    }
}

extern "C" void kernel_launch(void* const* d_in, const int* in_sizes, int n_in,
                              void* d_out, int out_size, void* d_ws, size_t ws_size,
                              hipStream_t stream)
{
  (void)in_sizes; (void)n_in; (void)out_size; (void)ws_size;
  const float* x     = (const float*)d_in[0];
  const float* g1    = (const float*)d_in[1];
  const float* b1    = (const float*)d_in[2];
  const float* qkv_w = (const float*)d_in[3];
  const float* qkv_b = (const float*)d_in[4];
  const float* pw    = (const float*)d_in[5];
  const float* pb    = (const float*)d_in[6];
  const float* ls    = (const float*)d_in[7];
  const float* rpb   = (const float*)d_in[8];
  const float* g2    = (const float*)d_in[9];
  const float* b2    = (const float*)d_in[10];
  const float* w1    = (const float*)d_in[11];
  const float* fb1   = (const float*)d_in[12];
  const float* w2    = (const float*)d_in[13];
  const float* fb2   = (const float*)d_in[14];
  float* out = (float*)d_out;

  const size_t n = (size_t)BV_*T_*D_;          // 13,107,200
  char* ws = (char*)d_ws;
  _Float16* qb  = (_Float16*)ws;               // n fp16
  _Float16* kb  = (_Float16*)(ws + n*2);       // n fp16
  float*    xf2 = (float*)(ws + n*4);          // n fp32 (proj+residual out)
  _Float16* vt  = (_Float16*)(ws + n*8);       // n fp16, PV-B-frag layout
  short*    xab = (short*)(ws + n*10);         // n bf16 (attn out)
  short*    qkv_wt = (short*)(ws + n*12);      // 384*128 bf16
  short*    pwt    = qkv_wt + 384*128;         // 128*128 bf16
  _Float16* w1t    = (_Float16*)(pwt + 128*128);   // 512*128 f16
  _Float16* w2t    = w1t + 512*128;                // 128*512 f16 frag-linear

  k0_prep  <<<256,          dim3(256), 0, stream>>>(qkv_w, pw, w1, w2, qkv_wt, pwt, w1t, w2t);
  k1_ln_qkv<<<BV_*(T_/64),  dim3(256), 0, stream>>>(x, g1, b1, qkv_wt, qkv_b, ls, qb, kb, vt);
  k2_attn  <<<BV_*H_,       dim3(256), 0, stream>>>(rpb, qb, kb, vt, xab);
  k3_proj  <<<BV_*(T_/64),  dim3(256), 0, stream>>>(x, xab, pwt, pb, xf2);
  k4_ffn   <<<BV_*(T_/128), dim3(256), 0, stream>>>(xf2, g2, b2, w1t, fb1, w2t, fb2, out);
}